// Round 6
// baseline (319.341 us; speedup 1.0000x reference)
//
#include <hip/hip_runtime.h>
#include <stdint.h>
#include <stddef.h>

// Problem dims (fixed by reference)
#define BB 8192
#define TT 26
#define VV 23
#define EE 100
#define HH 128
#define LL 64

typedef __attribute__((ext_vector_type(8))) short bf16x8;  // 8 bf16 = 4 VGPRs
typedef __attribute__((ext_vector_type(4))) float f32x4;   // MFMA 16x16 C/D

#define MFMA(a, b, c) __builtin_amdgcn_mfma_f32_16x16x32_bf16((a), (b), (c), 0, 0, 0)

// ---------------- workspace layout (bytes) ----------------
#define OFF_GRUW   0ull                  // GRU Whh B-frags: 24ct*4kc*1024
#define OFF_TBL    98304ull              // one-hot table B-frags: 24ct*1024 (bih + bhh_r/z folded)
#define OFF_LSTMW  122880ull             // LSTM fused W B-frags: 28ct*8kc*1024 (kc0-3=y, kc4-7=h)
#define OFF_OUTW   352256ull             // out_w B-frags: 2ct*4kc*1024
#define OFF_FCZW   360448ull             // fc_z_w B-frags: 8ct*2kc*1024
#define OFF_LBIAS  376832ull             // fused LSTM bias 4*112 fp32

// Dynamic-LDS partition (bytes) — M=32, TRIPLE-buffered y/h, decoupled sync
#define L_LW    0              // LSTM h-half weight frags kc4-6: 84 KB (28ct*3kc*1024)
#define L_HF    86016          // GRU y tri-buf: 3 * 8192
#define L_LH    110592         // LSTM h tri-buf: 3 * 8192
#define L_IDX   135168         // token idx: TT*32 = 832 (padded 1024)
#define L_CNT   136192         // 3 phase counters (64B apart) + pad
#define L_TOTAL 136448

__device__ __forceinline__ void force_frag(bf16x8& v) { asm volatile("" : "+v"(v)); }

// Exact RNE (prep only)
__device__ __forceinline__ unsigned short f2bf(float f) {
  union { float f; unsigned u; } v; v.f = f;
  unsigned u = v.u;
  return (unsigned short)((u + 0x7FFFu + ((u >> 16) & 1u)) >> 16);
}
// Fast in-loop convert (round-half-up)
__device__ __forceinline__ unsigned short f2bf_fast(float f) {
  union { float f; unsigned u; } v; v.f = f;
  return (unsigned short)((v.u + 0x8000u) >> 16);
}
#define LOG2E 1.4426950408889634f
__device__ __forceinline__ float sigm(float x) {
  return __builtin_amdgcn_rcpf(1.0f + __builtin_amdgcn_exp2f(-x * LOG2E));
}
__device__ __forceinline__ float tanh_(float x) {
  return __builtin_fmaf(-2.0f,
      __builtin_amdgcn_rcpf(1.0f + __builtin_amdgcn_exp2f(x * (2.0f * LOG2E))), 1.0f);
}

// -------- decoupled-pipeline sync primitives (LDS counters) --------
// R5 FIX: self-waits must execute EVERY iteration (incl. epilogue) so the
// aggregate counter faithfully encodes "all waves of role completed phase
// p-1". R2's un-gated epilogue posts let fast waves inflate the sum while
// a straggler was still writing its last tile (race on y(25)/h(25)).
__device__ __forceinline__ void wait_ge(int* cnt, int tgt) {
  while (__hip_atomic_load(cnt, __ATOMIC_ACQUIRE, __HIP_MEMORY_SCOPE_WORKGROUP) < tgt)
    __builtin_amdgcn_s_sleep(2);
  __builtin_amdgcn_sched_barrier(0);   // forbid hoisting data ds_reads above the spin
}
__device__ __forceinline__ void post_cnt(int* cnt, int lane) {
  __threadfence_block();     // drain this wave's LDS writes before publishing
  if (lane == 0)
    __hip_atomic_fetch_add(cnt, 1, __ATOMIC_RELEASE, __HIP_MEMORY_SCOPE_WORKGROUP);
}

// =====================================================================
// K0: ALL prep (weight swizzles + one-hot table) in ONE kernel.
//   blocks 0..689   : main swizzles (e = blk*256 + tid)
//   blocks 690..737 : one-hot table, 2 blocks per ct (half each)
// =====================================================================
__global__ __launch_bounds__(256) void prep_kernel(
    const float* __restrict__ fc_z_w, const float* __restrict__ gru_whh,
    const float* __restrict__ lstm_wih, const float* __restrict__ lstm_whh,
    const float* __restrict__ lstm_bih, const float* __restrict__ lstm_bhh,
    const float* __restrict__ out_w,
    const float* __restrict__ emb, const float* __restrict__ gru_wih,
    const float* __restrict__ gru_bih, const float* __restrict__ gru_bhh,
    char* __restrict__ ws)
{
  __shared__ float emb_s[VV * EE];
  __shared__ float wih_s[16 * EE];
  __shared__ float bih_s[16];
  const int blk = blockIdx.x;
  const int tid = threadIdx.x;

  if (blk >= 690) {
    // ---------------- one-hot table part ----------------
    const int blk2 = blk - 690;          // 0..47
    const int ct   = blk2 >> 1;          // 0..23
    const int half = blk2 & 1;
    const int n0   = ct * 16;

    for (int i = tid; i < VV * EE; i += 256) emb_s[i] = emb[i];
    for (int i = tid; i < 16 * EE; i += 256) wih_s[i] = gru_wih[n0 * EE + i];
    if (tid < 16) bih_s[tid] = gru_bih[n0 + tid];
    __syncthreads();

    const int t512 = half * 256 + tid;   // 0..511 within ct
    const int j    = t512 & 7;
    const int lane = (t512 >> 3) & 63;
    const int n16  = lane & 15;
    const int k    = ((lane >> 4) & 3) * 8 + j;
    const int g    = ct >> 3;            // gate 0=r 1=z 2=n
    float v = 0.0f;
    if (k < VV) {
      const float* ep = emb_s + k * EE;
      const float* wp = wih_s + n16 * EE;
      float s0 = 0.f, s1 = 0.f, s2 = 0.f, s3 = 0.f;
#pragma unroll 5
      for (int m = 0; m < EE; m += 4) {
        s0 += ep[m] * wp[m];         s1 += ep[m + 1] * wp[m + 1];
        s2 += ep[m + 2] * wp[m + 2]; s3 += ep[m + 3] * wp[m + 3];
      }
      v = bih_s[n16] + ((s0 + s1) + (s2 + s3));
      // fold gru_bhh for r,z gates (added exactly once per selected row);
      // n-gate bhh stays in the h-path (multiplied by r), not folded.
      if (g < 2) v += gru_bhh[g * HH + (ct & 7) * 16 + n16];
    }
    *(unsigned short*)(ws + OFF_TBL + (size_t)(ct * 512 + t512) * 2) = f2bf(v);
    return;
  }

  // ---------------- main swizzle part ----------------
  int e = blk * 256 + tid;

  if (e < 49152) {  // GRU Whh (384x128)
    int j = e & 7, lane = (e >> 3) & 63, kc = (e >> 9) & 3, ct = e >> 11;
    int n = ct * 16 + (lane & 15);
    int k = kc * 32 + ((lane >> 4) & 3) * 8 + j;
    *(unsigned short*)(ws + OFF_GRUW + (size_t)e * 2) = f2bf(gru_whh[n * HH + k]);
    return;
  }
  e -= 49152;
  if (e < 114688) {  // LSTM fused W: row=112g+c, K=[y 0..127 | h 0..127]
    int j = e & 7, lane = (e >> 3) & 63, kc = (e >> 9) & 7, ct = e >> 12;
    int row = ct * 16 + (lane & 15);
    int g = row / 112, c = row % 112;
    int q = (lane >> 4) & 3;
    float v = 0.0f;
    if (c < EE) {
      if (kc < 4) {
        int k = kc * 32 + q * 8 + j;
        v = lstm_wih[(g * EE + c) * HH + k];
      } else {
        int k = (kc - 4) * 32 + q * 8 + j;
        if (k < EE) v = lstm_whh[(g * EE + c) * EE + k];
      }
    }
    *(unsigned short*)(ws + OFF_LSTMW + (size_t)e * 2) = f2bf(v);
    return;
  }
  e -= 114688;
  if (e < 4096) {  // out_w (23x100 -> 32x128)
    int j = e & 7, lane = (e >> 3) & 63, kc = (e >> 9) & 3, ct = e >> 11;
    int n = ct * 16 + (lane & 15);
    int k = kc * 32 + ((lane >> 4) & 3) * 8 + j;
    float v = (n < VV && k < EE) ? out_w[n * EE + k] : 0.0f;
    *(unsigned short*)(ws + OFF_OUTW + (size_t)e * 2) = f2bf(v);
    return;
  }
  e -= 4096;
  if (e < 8192) {  // fc_z_w (128x64)
    int j = e & 7, lane = (e >> 3) & 63, kc = (e >> 9) & 1, ct = e >> 10;
    int n = ct * 16 + (lane & 15);
    int k = kc * 32 + ((lane >> 4) & 3) * 8 + j;
    *(unsigned short*)(ws + OFF_FCZW + (size_t)e * 2) = f2bf(fc_z_w[n * LL + k]);
    return;
  }
  e -= 8192;
  if (e < 448) {  // fused LSTM bias
    int g = e / 112, c = e % 112;
    float v = (c < EE) ? (lstm_bih[g * EE + c] + lstm_bhh[g * EE + c]) : 0.0f;
    *(float*)(ws + OFF_LBIAS + (size_t)e * 4) = v;
  }
}

// =====================================================================
// K1: FUSED gru+lstm+logits. 256 blocks x 1024 thr (16 waves), 32 rows.
// Decoupled pipeline (R2) + R5 sum-integrity fix: per-role self-wait on
// EVERY iteration (incl. epilogue) keeps counter sums faithful.
// Dep graph (phase p):
//   GRU  p: y(p)   = f(y(p-1));  self cg>=8p; cl>=7(p-1) for buf reuse
//   LSTM p: h(p-1) = f(y(p-1), h(p-2)); self cl>=7p; cg>=8p; co>=p-1
//   LOG  p: out(p-2) = f(h(p-2)); cl>=7p
//   y(t) in hfrag[t%3]  (h0 = y(-1) in buf 2);  h(t) in lhbuf[t%3]
// =====================================================================
__global__ __launch_bounds__(1024, 4) void fused_kernel(
    const float* __restrict__ z, const int* __restrict__ x_in,
    const float* __restrict__ fc_z_b, const float* __restrict__ gru_bhh,
    const unsigned short* __restrict__ gruw, const unsigned short* __restrict__ tbl,
    const unsigned short* __restrict__ fczw,
    const unsigned short* __restrict__ lstmw, const float* __restrict__ lbias,
    const float* __restrict__ out_b, const unsigned short* __restrict__ outw,
    float* __restrict__ out)
{
  extern __shared__ char smem[];
  unsigned short* lwlds = (unsigned short*)(smem + L_LW);   // h-half kc4-6 weight frags
  char*           hfrag = smem + L_HF;                      // 3 bufs * 8192 B
  char*           lhbuf = smem + L_LH;                      // 3 bufs * 8192 B
  unsigned char*  idx_lds = (unsigned char*)(smem + L_IDX);
  int*            cnts  = (int*)(smem + L_CNT);
  int* cg = cnts + 0;    // GRU phases completed  (x8 waves)
  int* cl = cnts + 16;   // LSTM phases completed (x7 waves)
  int* co = cnts + 32;   // logits phases completed (x1 wave)

  const int tid  = threadIdx.x;
  const int wv   = tid >> 6;        // 0..15
  const int lane = tid & 63;
  const int l15  = lane & 15;
  const int q    = (lane >> 4) & 3;
  const int blk  = blockIdx.x;      // 0..255

  // cooperative init: counters, zero h(-1) (all 3 h bufs), stage kc4-6 weights
  if (tid < 48) cnts[tid] = 0;
  for (int i = tid; i < 12288; i += 1024)
    ((unsigned short*)lhbuf)[i] = 0;
  for (int f = tid; f < 5376; f += 1024) {          // 5376 b128 chunks = 84 KB
    int frag_i = f >> 6, within = f & 63;           // frag_i = ct*3 + kcl
    int ct = frag_i / 3, kcl = frag_i % 3;
    *(bf16x8*)((char*)lwlds + (size_t)frag_i * 1024 + within * 16) =
        *(const bf16x8*)(lstmw + ((size_t)(ct * 8 + 4 + kcl)) * 512 + within * 8);
  }

  if (wv < 8) {
    // ================= GRU role =================
    {
      int rid = wv * 64 + lane;     // 0..511
      for (int i = rid; i < TT * 32; i += 512) {
        int t = i >> 5, r = i & 31;
        idx_lds[i] = (unsigned char)x_in[(blk * 32 + r) * TT + t];
      }
    }
    bf16x8 gw[3][4], tw[3];
#pragma unroll
    for (int g = 0; g < 3; g++) {
      int ct = g * 8 + wv;
#pragma unroll
      for (int kc = 0; kc < 4; kc++) {
        gw[g][kc] = *(const bf16x8*)(gruw + (size_t)(ct * 4 + kc) * 512 + lane * 8);
        force_frag(gw[g][kc]);
      }
      tw[g] = *(const bf16x8*)(tbl + (size_t)ct * 512 + lane * 8);
      force_frag(tw[g]);
    }
    const int col = wv * 16 + l15;
    const float b_n = gru_bhh[2 * HH + col];   // r,z biases folded into tbl
    const int wbase = (col >> 5) * 512 + ((col >> 3) & 3) * 128 + (col & 7);

    // h0 = tanh(z @ fc_z_w^T + fc_z_b)  ->  hfrag buf 2 ("y(-1)")
    float h[2][4];
    {
      bf16x8 fw0 = *(const bf16x8*)(fczw + (size_t)(wv * 2 + 0) * 512 + lane * 8);
      bf16x8 fw1 = *(const bf16x8*)(fczw + (size_t)(wv * 2 + 1) * 512 + lane * 8);
      float fzb = fc_z_b[col];
#pragma unroll
      for (int mt = 0; mt < 2; mt++) {
        const float* zp = z + (size_t)(blk * 32 + mt * 16 + l15) * LL + q * 8;
        f32x4 z0 = *(const f32x4*)(zp);
        f32x4 z1 = *(const f32x4*)(zp + 4);
        f32x4 z2 = *(const f32x4*)(zp + 32);
        f32x4 z3 = *(const f32x4*)(zp + 36);
        bf16x8 za0, za1;
#pragma unroll
        for (int j = 0; j < 4; j++) {
          za0[j]     = (short)f2bf(z0[j]);
          za0[4 + j] = (short)f2bf(z1[j]);
          za1[j]     = (short)f2bf(z2[j]);
          za1[4 + j] = (short)f2bf(z3[j]);
        }
        f32x4 acc = {fzb, fzb, fzb, fzb};
        acc = MFMA(za0, fw0, acc);
        acc = MFMA(za1, fw1, acc);
#pragma unroll
        for (int i = 0; i < 4; i++) {
          h[mt][i] = tanh_(acc[i]);
          ((unsigned short*)(hfrag + 2 * 8192 + mt * 4096))[wbase + (q * 4 + i) * 8]
              = f2bf_fast(h[mt][i]);
        }
      }
    }
    __syncthreads();                              // barrier A (init complete)

#pragma unroll 1
    for (int p = 0; p < TT + 2; p++) {
      wait_ge(cg, 8 * p);                         // self-lockstep, EVERY iter
      if (p >= 3 && p < TT) wait_ge(cl, 7 * (p - 1));  // LSTM consumed y(p-3)
      if (p < TT) {
        const int br = (p + 2) % 3;               // y(p-1)
        const int bw = (p + 3) % 3;               // y(p)
#pragma unroll
        for (int mt = 0; mt < 2; mt++) {
          int iv = idx_lds[p * 32 + mt * 16 + l15];
          bf16x8 oh;
#pragma unroll
          for (int j = 0; j < 8; j++)
            oh[j] = (short)((iv == q * 8 + j) ? 0x3F80 : 0);

          f32x4 ar  = {0.0f, 0.0f, 0.0f, 0.0f};   // bhh_r folded into tbl
          f32x4 az  = {0.0f, 0.0f, 0.0f, 0.0f};   // bhh_z folded into tbl
          f32x4 ahn = {b_n, b_n, b_n, b_n};
          f32x4 axn = {0.0f, 0.0f, 0.0f, 0.0f};
          ar  = MFMA(oh, tw[0], ar);
          az  = MFMA(oh, tw[1], az);
          axn = MFMA(oh, tw[2], axn);

          bf16x8 a[4];
#pragma unroll
          for (int kc = 0; kc < 4; kc++)
            a[kc] = *(const bf16x8*)(hfrag + br * 8192 + mt * 4096
                                     + kc * 1024 + lane * 16);
#pragma unroll
          for (int kc = 0; kc < 4; kc++) {
            ar  = MFMA(a[kc], gw[0][kc], ar);
            az  = MFMA(a[kc], gw[1][kc], az);
            ahn = MFMA(a[kc], gw[2][kc], ahn);
          }
#pragma unroll
          for (int i = 0; i < 4; i++) {
            float r  = sigm(ar[i]);
            float zg = sigm(az[i]);
            float n  = tanh_(__builtin_fmaf(r, ahn[i], axn[i]));
            h[mt][i] = __builtin_fmaf(zg, h[mt][i] - n, n);
            ((unsigned short*)(hfrag + bw * 8192 + mt * 4096))
                [wbase + (q * 4 + i) * 8] = f2bf_fast(h[mt][i]);
          }
        }
      }
      post_cnt(cg, lane);
    }
  } else if (wv < 15) {
    // ================= LSTM role =================
    const int tile = wv - 8;        // 0..6
    // y-half weights kc0..3 in registers (64 regs)
    bf16x8 lwy[4][4];
#pragma unroll
    for (int g = 0; g < 4; g++)
#pragma unroll
      for (int kc = 0; kc < 4; kc++) {
        lwy[g][kc] = *(const bf16x8*)(lstmw + (size_t)((g * 7 + tile) * 8 + kc) * 512 + lane * 8);
        force_frag(lwy[g][kc]);
      }
    const int col = tile * 16 + l15;
    float b[4];
#pragma unroll
    for (int g = 0; g < 4; g++) b[g] = lbias[g * 112 + col];
    const int wbase = (col >> 5) * 512 + ((col >> 3) & 3) * 128 + (col & 7);
    float c[2][4] = {{0, 0, 0, 0}, {0, 0, 0, 0}};
    __syncthreads();                              // barrier A

#pragma unroll 1
    for (int p = 0; p < TT + 2; p++) {
      wait_ge(cl, 7 * p);                         // self-lockstep, EVERY iter
      if (p >= 1 && p <= TT) {
        wait_ge(cg, 8 * p);                       // y(p-1) ready
        if (p >= 4) wait_ge(co, p - 1);           // logits consumed h(p-4)
        const int by = (p + 2) % 3;               // y(p-1)
        const int bh = (p + 1) % 3;               // h(p-2)
        const int bw2 = (p + 2) % 3;              // h(p-1) write
#pragma unroll
        for (int mt = 0; mt < 2; mt++) {
          f32x4 acc[4];
#pragma unroll
          for (int g = 0; g < 4; g++) {
            f32x4 ini = {b[g], b[g], b[g], b[g]};
            acc[g] = ini;
          }
          // y-half: reg weights
#pragma unroll
          for (int kc = 0; kc < 4; kc++) {
            bf16x8 ya = *(const bf16x8*)(hfrag + by * 8192 + mt * 4096
                                         + kc * 1024 + lane * 16);
            acc[0] = MFMA(ya, lwy[0][kc], acc[0]);
            acc[1] = MFMA(ya, lwy[1][kc], acc[1]);
            acc[2] = MFMA(ya, lwy[2][kc], acc[2]);
            acc[3] = MFMA(ya, lwy[3][kc], acc[3]);
          }
          // h-half: kc0-2 weights from LDS, kc3 from global (L1-hot, mostly-zero pad)
#pragma unroll
          for (int kc = 0; kc < 4; kc++) {
            bf16x8 ha = *(const bf16x8*)(lhbuf + bh * 8192 + mt * 4096
                                         + kc * 1024 + lane * 16);
            bf16x8 w0, w1, w2, w3;
            if (kc < 3) {
              const char* wb = (const char*)lwlds + (size_t)(tile * 3 + kc) * 1024 + lane * 16;
              w0 = *(const bf16x8*)(wb);
              w1 = *(const bf16x8*)(wb + 21504);    // gate stride 7*3*1024
              w2 = *(const bf16x8*)(wb + 2 * 21504);
              w3 = *(const bf16x8*)(wb + 3 * 21504);
            } else {
              w0 = *(const bf16x8*)(lstmw + (size_t)((0 * 7 + tile) * 8 + 7) * 512 + lane * 8);
              w1 = *(const bf16x8*)(lstmw + (size_t)((1 * 7 + tile) * 8 + 7) * 512 + lane * 8);
              w2 = *(const bf16x8*)(lstmw + (size_t)((2 * 7 + tile) * 8 + 7) * 512 + lane * 8);
              w3 = *(const bf16x8*)(lstmw + (size_t)((3 * 7 + tile) * 8 + 7) * 512 + lane * 8);
            }
            acc[0] = MFMA(ha, w0, acc[0]);
            acc[1] = MFMA(ha, w1, acc[1]);
            acc[2] = MFMA(ha, w2, acc[2]);
            acc[3] = MFMA(ha, w3, acc[3]);
          }
#pragma unroll
          for (int i = 0; i < 4; i++) {
            float ii = sigm(acc[0][i]), ff = sigm(acc[1][i]);
            float gg = tanh_(acc[2][i]), oo = sigm(acc[3][i]);
            float cn = __builtin_fmaf(ff, c[mt][i], ii * gg);
            c[mt][i] = cn;
            ((unsigned short*)(lhbuf + bw2 * 8192 + mt * 4096))
                [wbase + (q * 4 + i) * 8] = f2bf_fast(oo * tanh_(cn));
          }
        }
      }
      post_cnt(cl, lane);
    }
  } else {
    // ================= logits role =================
    bf16x8 ow[2][4];
#pragma unroll
    for (int ct = 0; ct < 2; ct++)
#pragma unroll
      for (int kc = 0; kc < 4; kc++) {
        ow[ct][kc] = *(const bf16x8*)(outw + (size_t)(ct * 4 + kc) * 512 + lane * 8);
        force_frag(ow[ct][kc]);
      }
    float ob[2];
#pragma unroll
    for (int ct = 0; ct < 2; ct++) {
      int cv = ct * 16 + l15;
      ob[ct] = (cv < VV) ? out_b[cv] : 0.0f;
    }
    __syncthreads();                              // barrier A

#pragma unroll 1
    for (int p = 0; p < TT + 2; p++) {
      if (p >= 2) {
        wait_ge(cl, 7 * p);                       // h(p-2) ready
        const int bh = (p + 1) % 3;
        const int t = p - 2;
#pragma unroll
        for (int mt = 0; mt < 2; mt++) {
          bf16x8 ha[4];
#pragma unroll
          for (int kc = 0; kc < 4; kc++)
            ha[kc] = *(const bf16x8*)(lhbuf + bh * 8192 + mt * 4096
                                      + kc * 1024 + lane * 16);
#pragma unroll
          for (int ct = 0; ct < 2; ct++) {
            f32x4 acc = {ob[ct], ob[ct], ob[ct], ob[ct]};
#pragma unroll
            for (int kc = 0; kc < 4; kc++)
              acc = MFMA(ha[kc], ow[ct][kc], acc);
            int cv = ct * 16 + l15;
            if (cv < VV) {
#pragma unroll
              for (int i = 0; i < 4; i++) {
                int rowg = blk * 32 + mt * 16 + q * 4 + i;
                out[((size_t)rowg * TT + t) * VV + cv] = acc[i];
              }
            }
          }
        }
      }
      post_cnt(co, lane);
    }
  }
}

extern "C" void kernel_launch(void* const* d_in, const int* in_sizes, int n_in,
                              void* d_out, int out_size, void* d_ws, size_t ws_size,
                              hipStream_t stream) {
  (void)in_sizes; (void)n_in; (void)out_size; (void)ws_size;
  const float* z        = (const float*)d_in[0];
  const int*   x_in     = (const int*)  d_in[1];
  const float* emb      = (const float*)d_in[2];
  const float* fc_z_w   = (const float*)d_in[3];
  const float* fc_z_b   = (const float*)d_in[4];
  const float* gru_wih  = (const float*)d_in[5];
  const float* gru_whh  = (const float*)d_in[6];
  const float* gru_bih  = (const float*)d_in[7];
  const float* gru_bhh  = (const float*)d_in[8];
  const float* lstm_wih = (const float*)d_in[9];
  const float* lstm_whh = (const float*)d_in[10];
  const float* lstm_bih = (const float*)d_in[11];
  const float* lstm_bhh = (const float*)d_in[12];
  const float* out_w    = (const float*)d_in[13];
  const float* out_b    = (const float*)d_in[14];
  char*  ws  = (char*)d_ws;
  float* out = (float*)d_out;

  const unsigned short* gruw  = (const unsigned short*)(ws + OFF_GRUW);
  const unsigned short* tblp  = (const unsigned short*)(ws + OFF_TBL);
  const unsigned short* lstmw = (const unsigned short*)(ws + OFF_LSTMW);
  const unsigned short* outw  = (const unsigned short*)(ws + OFF_OUTW);
  const unsigned short* fczw  = (const unsigned short*)(ws + OFF_FCZW);
  const float*          lbias = (const float*)(ws + OFF_LBIAS);

  // allow >64 KB dynamic LDS (idempotent; not a stream op, capture-safe)
  hipFuncSetAttribute((const void*)fused_kernel,
                      hipFuncAttributeMaxDynamicSharedMemorySize, L_TOTAL);

  prep_kernel<<<738, 256, 0, stream>>>(fc_z_w, gru_whh, lstm_wih, lstm_whh,
                                       lstm_bih, lstm_bhh, out_w,
                                       emb, gru_wih, gru_bih, gru_bhh, ws);
  fused_kernel<<<256, 1024, L_TOTAL, stream>>>(z, x_in, fc_z_b, gru_bhh,
                                               gruw, tblp, fczw, lstmw, lbias,
                                               out_b, outw, out);
}

// Round 7
// 187.336 us; speedup vs baseline: 1.7046x; 1.7046x over previous
//
#include <hip/hip_runtime.h>
#include <stdint.h>
#include <stddef.h>

// Problem dims (fixed by reference)
#define BB 8192
#define TT 26
#define VV 23
#define EE 100
#define HH 128
#define LL 64

typedef __attribute__((ext_vector_type(8))) short bf16x8;  // 8 bf16 = 4 VGPRs
typedef __attribute__((ext_vector_type(4))) float f32x4;   // MFMA 16x16 C/D

#define MFMA(a, b, c) __builtin_amdgcn_mfma_f32_16x16x32_bf16((a), (b), (c), 0, 0, 0)

// ---------------- workspace layout (bytes) ----------------
#define OFF_GRUW   0ull                  // GRU Whh B-frags: 24ct*4kc*1024
#define OFF_TBL    98304ull              // one-hot table B-frags: 24ct*1024 (bih + bhh_r/z folded)
#define OFF_LSTMW  122880ull             // LSTM fused W B-frags: 28ct*8kc*1024 (kc0-3=y, kc4-7=h)
#define OFF_OUTW   352256ull             // out_w B-frags: 2ct*4kc*1024
#define OFF_FCZW   360448ull             // fc_z_w B-frags: 8ct*2kc*1024
#define OFF_LBIAS  376832ull             // fused LSTM bias 4*112 fp32

// Dynamic-LDS partition (bytes) — M=32 rows/block (R1 layout, proven 108.5us)
#define L_LW    0              // LSTM h-half weight frags: 112 KB (28 ct * 4 kc * 1024)
#define L_HF    114688         // GRU y dbuf: 2 * 8192 (2 row-tiles * 4096)
#define L_LH    131072         // LSTM h dbuf: 2 * 8192
#define L_IDX   147456         // token idx: TT*32 = 832 (padded to 1024)
#define L_TOTAL 148480

__device__ __forceinline__ void force_frag(bf16x8& v) { asm volatile("" : "+v"(v)); }

// Exact RNE (prep only)
__device__ __forceinline__ unsigned short f2bf(float f) {
  union { float f; unsigned u; } v; v.f = f;
  unsigned u = v.u;
  return (unsigned short)((u + 0x7FFFu + ((u >> 16) & 1u)) >> 16);
}
// Fast in-loop convert (round-half-up)
__device__ __forceinline__ unsigned short f2bf_fast(float f) {
  union { float f; unsigned u; } v; v.f = f;
  return (unsigned short)((v.u + 0x8000u) >> 16);
}
#define LOG2E 1.4426950408889634f
__device__ __forceinline__ float sigm(float x) {
  return __builtin_amdgcn_rcpf(1.0f + __builtin_amdgcn_exp2f(-x * LOG2E));
}
__device__ __forceinline__ float tanh_(float x) {
  return __builtin_fmaf(-2.0f,
      __builtin_amdgcn_rcpf(1.0f + __builtin_amdgcn_exp2f(x * (2.0f * LOG2E))), 1.0f);
}

__device__ __forceinline__ bf16x8 cvt8(f32x4 a, f32x4 b) {
  bf16x8 o;
#pragma unroll
  for (int j = 0; j < 4; j++) {
    o[j]     = (short)f2bf(a[j]);
    o[4 + j] = (short)f2bf(b[j]);
  }
  return o;
}

// =====================================================================
// K0 (R6): vectorized prep. Each thread builds one 16-B bf16x8 fragment
// chunk from two aligned f32x4 global loads (swizzle is contiguous in j).
//   blocks 0..85    : frag chunks (22016 = 86*256)
//                     [0,6144)      GRUW
//                     [6144,20480)  LSTMW
//                     [20480,20992) OUTW
//                     [20992,22016) FCZW
//   blocks 86..87   : fused LSTM bias (448 floats)
//   blocks 88..135  : one-hot table, 2 blocks per ct
// =====================================================================
__global__ __launch_bounds__(256) void prep_kernel(
    const float* __restrict__ fc_z_w, const float* __restrict__ gru_whh,
    const float* __restrict__ lstm_wih, const float* __restrict__ lstm_whh,
    const float* __restrict__ lstm_bih, const float* __restrict__ lstm_bhh,
    const float* __restrict__ out_w,
    const float* __restrict__ emb, const float* __restrict__ gru_wih,
    const float* __restrict__ gru_bih, const float* __restrict__ gru_bhh,
    char* __restrict__ ws)
{
  __shared__ float emb_s[VV * EE];
  __shared__ float wih_s[16 * EE];
  __shared__ float bih_s[16];
  const int blk = blockIdx.x;
  const int tid = threadIdx.x;

  if (blk < 86) {
    const int ch = blk * 256 + tid;          // 0..22015
    bf16x8 o = {0, 0, 0, 0, 0, 0, 0, 0};
    if (ch < 6144) {
      // ---- GRUW (384x128): e = ch*8+j; j contiguous in k ----
      int lane = ch & 63, kc = (ch >> 6) & 3, ct = ch >> 8;
      int n  = ct * 16 + (lane & 15);
      int k0 = kc * 32 + ((lane >> 4) & 3) * 8;
      const float* s = gru_whh + (size_t)n * HH + k0;
      o = cvt8(*(const f32x4*)s, *(const f32x4*)(s + 4));
      ((bf16x8*)(ws + OFF_GRUW))[ch] = o;
    } else if (ch < 20480) {
      // ---- LSTMW fused (row=112g+c, K=[y 0..127 | h 0..127]) ----
      int c2 = ch - 6144;
      int lane = c2 & 63, kc = (c2 >> 6) & 7, ct = c2 >> 9;
      int row = ct * 16 + (lane & 15);
      int g = row / 112, cc = row % 112;
      int q = (lane >> 4) & 3;
      if (cc < EE) {
        if (kc < 4) {
          const float* s = lstm_wih + (size_t)(g * EE + cc) * HH + kc * 32 + q * 8;
          o = cvt8(*(const f32x4*)s, *(const f32x4*)(s + 4));
        } else {
          int k0 = (kc - 4) * 32 + q * 8;
          const float* s = lstm_whh + (size_t)(g * EE + cc) * EE + k0;
          if (k0 + 8 <= EE) {
            o = cvt8(*(const f32x4*)s, *(const f32x4*)(s + 4));
          } else if (k0 < EE) {     // k0 == 96: 4 valid elements
            f32x4 a = *(const f32x4*)s;
#pragma unroll
            for (int j = 0; j < 4; j++) o[j] = (short)f2bf(a[j]);
          }
        }
      }
      ((bf16x8*)(ws + OFF_LSTMW))[c2] = o;
    } else if (ch < 20992) {
      // ---- OUTW (23x100 -> 32x128) ----
      int c3 = ch - 20480;
      int lane = c3 & 63, kc = (c3 >> 6) & 3, ct = c3 >> 8;
      int n  = ct * 16 + (lane & 15);
      int k0 = kc * 32 + ((lane >> 4) & 3) * 8;
      if (n < VV) {
        const float* s = out_w + (size_t)n * EE + k0;
        if (k0 + 8 <= EE) {
          o = cvt8(*(const f32x4*)s, *(const f32x4*)(s + 4));
        } else if (k0 < EE) {       // k0 == 96
          f32x4 a = *(const f32x4*)s;
#pragma unroll
          for (int j = 0; j < 4; j++) o[j] = (short)f2bf(a[j]);
        }
      }
      ((bf16x8*)(ws + OFF_OUTW))[c3] = o;
    } else {
      // ---- FCZW (128x64): k0+7 <= 63 always ----
      int c4 = ch - 20992;
      int lane = c4 & 63, kc = (c4 >> 6) & 1, ct = c4 >> 7;
      int n  = ct * 16 + (lane & 15);
      int k0 = kc * 32 + ((lane >> 4) & 3) * 8;
      const float* s = fc_z_w + (size_t)n * LL + k0;
      o = cvt8(*(const f32x4*)s, *(const f32x4*)(s + 4));
      ((bf16x8*)(ws + OFF_FCZW))[c4] = o;
    }
    return;
  }

  if (blk < 88) {
    // ---- fused LSTM bias ----
    int idx = (blk - 86) * 256 + tid;
    if (idx < 448) {
      int g = idx / 112, c = idx % 112;
      float v = (c < EE) ? (lstm_bih[g * EE + c] + lstm_bhh[g * EE + c]) : 0.0f;
      *(float*)(ws + OFF_LBIAS + (size_t)idx * 4) = v;
    }
    return;
  }

  // ---- one-hot table part (blocks 88..135; 2 per ct) ----
  const int blk2 = blk - 88;           // 0..47
  const int ct   = blk2 >> 1;          // 0..23
  const int half = blk2 & 1;
  const int n0   = ct * 16;

  for (int i = tid; i < VV * EE; i += 256) emb_s[i] = emb[i];
  for (int i = tid; i < 16 * EE; i += 256) wih_s[i] = gru_wih[n0 * EE + i];
  if (tid < 16) bih_s[tid] = gru_bih[n0 + tid];
  __syncthreads();

  const int t512 = half * 256 + tid;   // 0..511 within ct
  const int j    = t512 & 7;
  const int lane = (t512 >> 3) & 63;
  const int n16  = lane & 15;
  const int k    = ((lane >> 4) & 3) * 8 + j;
  const int g    = ct >> 3;            // gate 0=r 1=z 2=n
  float v = 0.0f;
  if (k < VV) {
    const float* ep = emb_s + k * EE;
    const float* wp = wih_s + n16 * EE;
    float s0 = 0.f, s1 = 0.f, s2 = 0.f, s3 = 0.f;
#pragma unroll 5
    for (int m = 0; m < EE; m += 4) {
      s0 += ep[m] * wp[m];         s1 += ep[m + 1] * wp[m + 1];
      s2 += ep[m + 2] * wp[m + 2]; s3 += ep[m + 3] * wp[m + 3];
    }
    v = bih_s[n16] + ((s0 + s1) + (s2 + s3));
    // fold gru_bhh for r,z gates (added exactly once per selected row);
    // n-gate bhh stays in the h-path (multiplied by r), not folded.
    if (g < 2) v += gru_bhh[g * HH + (ct & 7) * 16 + n16];
  }
  *(unsigned short*)(ws + OFF_TBL + (size_t)(ct * 512 + t512) * 2) = f2bf(v);
}

// =====================================================================
// K1: FUSED gru+lstm+logits. 256 blocks x 1024 thr (16 waves), 32 rows.
// R1 barrier version VERBATIM (measured 108.5us, passed). Decoupled-sync
// variants (R2-R5) regressed 2.3x (spin-poll coherence defeated L1/L2
// weight residency: FETCH 7.7MB -> 456MB). Barriers stay.
//   waves 0-7  (GRU):    step p      y(p)   -> hfrag[(p+1)&1]
//   waves 8-14 (LSTM):   step p-1    h(p-1) -> lhbuf[p&1]
//   wave 15    (logits): step p-2    -> out
// =====================================================================
__global__ __launch_bounds__(1024, 4) void fused_kernel(
    const float* __restrict__ z, const int* __restrict__ x_in,
    const float* __restrict__ fc_z_b, const float* __restrict__ gru_bhh,
    const unsigned short* __restrict__ gruw, const unsigned short* __restrict__ tbl,
    const unsigned short* __restrict__ fczw,
    const unsigned short* __restrict__ lstmw, const float* __restrict__ lbias,
    const float* __restrict__ out_b, const unsigned short* __restrict__ outw,
    float* __restrict__ out)
{
  extern __shared__ char smem[];
  unsigned short* lwlds = (unsigned short*)(smem + L_LW);   // h-half weight frags
  char*           hfrag = smem + L_HF;                      // [buf]*8192 B, tile mt at mt*4096
  char*           lhbuf = smem + L_LH;                      // [buf]*8192 B
  unsigned char*  idx_lds = (unsigned char*)(smem + L_IDX);

  const int tid  = threadIdx.x;
  const int wv   = tid >> 6;        // 0..15
  const int lane = tid & 63;
  const int l15  = lane & 15;
  const int q    = (lane >> 4) & 3;
  const int blk  = blockIdx.x;      // 0..255

  // cooperative: zero LSTM h state (both buffers) + stage h-half weight frags
  for (int i = tid; i < 8192; i += 1024)
    ((unsigned short*)lhbuf)[i] = 0;
  for (int f = tid; f < 7168; f += 1024) {          // 7168 b128 chunks = 112 KB
    int frag_i = f >> 6, within = f & 63;
    int ct = frag_i >> 2, kcl = frag_i & 3;
    *(bf16x8*)((char*)lwlds + (size_t)frag_i * 1024 + within * 16) =
        *(const bf16x8*)(lstmw + ((size_t)(ct * 8 + 4 + kcl)) * 512 + within * 8);
  }

  if (wv < 8) {
    // ================= GRU role =================
    {
      int rid = wv * 64 + lane;     // 0..511
      for (int i = rid; i < TT * 32; i += 512) {
        int t = i >> 5, r = i & 31;
        idx_lds[i] = (unsigned char)x_in[(blk * 32 + r) * TT + t];
      }
    }
    bf16x8 gw[3][4], tw[3];
#pragma unroll
    for (int g = 0; g < 3; g++) {
      int ct = g * 8 + wv;
#pragma unroll
      for (int kc = 0; kc < 4; kc++) {
        gw[g][kc] = *(const bf16x8*)(gruw + (size_t)(ct * 4 + kc) * 512 + lane * 8);
        force_frag(gw[g][kc]);
      }
      tw[g] = *(const bf16x8*)(tbl + (size_t)ct * 512 + lane * 8);
      force_frag(tw[g]);
    }
    const int col = wv * 16 + l15;
    const float b_n = gru_bhh[2 * HH + col];   // r,z biases folded into tbl
    const int wbase = (col >> 5) * 512 + ((col >> 3) & 3) * 128 + (col & 7);

    // h0 = tanh(z @ fc_z_w^T + fc_z_b), two row-tiles
    float h[2][4];
    {
      bf16x8 fw0 = *(const bf16x8*)(fczw + (size_t)(wv * 2 + 0) * 512 + lane * 8);
      bf16x8 fw1 = *(const bf16x8*)(fczw + (size_t)(wv * 2 + 1) * 512 + lane * 8);
      float fzb = fc_z_b[col];
#pragma unroll
      for (int mt = 0; mt < 2; mt++) {
        const float* zp = z + (size_t)(blk * 32 + mt * 16 + l15) * LL + q * 8;
        f32x4 z0 = *(const f32x4*)(zp);
        f32x4 z1 = *(const f32x4*)(zp + 4);
        f32x4 z2 = *(const f32x4*)(zp + 32);
        f32x4 z3 = *(const f32x4*)(zp + 36);
        bf16x8 za0, za1;
#pragma unroll
        for (int j = 0; j < 4; j++) {
          za0[j]     = (short)f2bf(z0[j]);
          za0[4 + j] = (short)f2bf(z1[j]);
          za1[j]     = (short)f2bf(z2[j]);
          za1[4 + j] = (short)f2bf(z3[j]);
        }
        f32x4 acc = {fzb, fzb, fzb, fzb};
        acc = MFMA(za0, fw0, acc);
        acc = MFMA(za1, fw1, acc);
#pragma unroll
        for (int i = 0; i < 4; i++) {
          h[mt][i] = tanh_(acc[i]);
          ((unsigned short*)(hfrag + mt * 4096))[wbase + (q * 4 + i) * 8]
              = f2bf_fast(h[mt][i]);
        }
      }
    }
    __syncthreads();                              // barrier A

    for (int p = 0; p < TT + 2; p++) {
      if (p < TT) {
#pragma unroll
        for (int mt = 0; mt < 2; mt++) {
          int iv = idx_lds[p * 32 + mt * 16 + l15];
          bf16x8 oh;
#pragma unroll
          for (int j = 0; j < 8; j++)
            oh[j] = (short)((iv == q * 8 + j) ? 0x3F80 : 0);

          f32x4 ar  = {0.0f, 0.0f, 0.0f, 0.0f};   // bhh_r folded into tbl
          f32x4 az  = {0.0f, 0.0f, 0.0f, 0.0f};   // bhh_z folded into tbl
          f32x4 ahn = {b_n, b_n, b_n, b_n};
          f32x4 axn = {0.0f, 0.0f, 0.0f, 0.0f};
          ar  = MFMA(oh, tw[0], ar);
          az  = MFMA(oh, tw[1], az);
          axn = MFMA(oh, tw[2], axn);

          bf16x8 a[4];
#pragma unroll
          for (int kc = 0; kc < 4; kc++)
            a[kc] = *(const bf16x8*)(hfrag + (p & 1) * 8192 + mt * 4096
                                     + kc * 1024 + lane * 16);
#pragma unroll
          for (int kc = 0; kc < 4; kc++) {
            ar  = MFMA(a[kc], gw[0][kc], ar);
            az  = MFMA(a[kc], gw[1][kc], az);
            ahn = MFMA(a[kc], gw[2][kc], ahn);
          }
#pragma unroll
          for (int i = 0; i < 4; i++) {
            float r  = sigm(ar[i]);
            float zg = sigm(az[i]);
            float n  = tanh_(__builtin_fmaf(r, ahn[i], axn[i]));
            h[mt][i] = __builtin_fmaf(zg, h[mt][i] - n, n);
            ((unsigned short*)(hfrag + ((p + 1) & 1) * 8192 + mt * 4096))
                [wbase + (q * 4 + i) * 8] = f2bf_fast(h[mt][i]);
          }
        }
      }
      __syncthreads();
    }
  } else if (wv < 15) {
    // ================= LSTM role =================
    const int tile = wv - 8;        // 0..6
    // y-half weights kc0..2 in registers (48 regs); kc3 streamed from global.
    bf16x8 lwy[4][3];
#pragma unroll
    for (int g = 0; g < 4; g++)
#pragma unroll
      for (int kc = 0; kc < 3; kc++) {
        lwy[g][kc] = *(const bf16x8*)(lstmw + (size_t)((g * 7 + tile) * 8 + kc) * 512 + lane * 8);
        force_frag(lwy[g][kc]);
      }
    const int col = tile * 16 + l15;
    float b[4];
#pragma unroll
    for (int g = 0; g < 4; g++) b[g] = lbias[g * 112 + col];
    const int wbase = (col >> 5) * 512 + ((col >> 3) & 3) * 128 + (col & 7);
    float c[2][4] = {{0, 0, 0, 0}, {0, 0, 0, 0}};
    __syncthreads();                              // barrier A

    for (int p = 0; p < TT + 2; p++) {
      if (p >= 1 && p <= TT) {
        // y-kc3 weights from global (L1-hot after step 0); issue early.
        bf16x8 yw3[4];
#pragma unroll
        for (int g = 0; g < 4; g++)
          yw3[g] = *(const bf16x8*)(lstmw + (size_t)((g * 7 + tile) * 8 + 3) * 512 + lane * 8);

        f32x4 acc[2][4];
#pragma unroll
        for (int mt = 0; mt < 2; mt++)
#pragma unroll
          for (int g = 0; g < 4; g++) {
            f32x4 ini = {b[g], b[g], b[g], b[g]};
            acc[mt][g] = ini;
          }

        // y-half kc0..2: reg weights, both row-tiles
#pragma unroll
        for (int kc = 0; kc < 3; kc++) {
          bf16x8 ya0 = *(const bf16x8*)(hfrag + (p & 1) * 8192 + 0 * 4096
                                        + kc * 1024 + lane * 16);
          bf16x8 ya1 = *(const bf16x8*)(hfrag + (p & 1) * 8192 + 1 * 4096
                                        + kc * 1024 + lane * 16);
#pragma unroll
          for (int g = 0; g < 4; g++) {
            acc[0][g] = MFMA(ya0, lwy[g][kc], acc[0][g]);
            acc[1][g] = MFMA(ya1, lwy[g][kc], acc[1][g]);
          }
        }
        // y-half kc3: streamed weights
        {
          bf16x8 ya0 = *(const bf16x8*)(hfrag + (p & 1) * 8192 + 0 * 4096
                                        + 3 * 1024 + lane * 16);
          bf16x8 ya1 = *(const bf16x8*)(hfrag + (p & 1) * 8192 + 1 * 4096
                                        + 3 * 1024 + lane * 16);
#pragma unroll
          for (int g = 0; g < 4; g++) {
            acc[0][g] = MFMA(ya0, yw3[g], acc[0][g]);
            acc[1][g] = MFMA(ya1, yw3[g], acc[1][g]);
          }
        }
        // h-half: LDS weights read ONCE per kc (shared across both row-tiles)
#pragma unroll
        for (int kc = 0; kc < 4; kc++) {
          const char* wb = (const char*)lwlds + (size_t)(tile * 4 + kc) * 1024 + lane * 16;
          bf16x8 w0 = *(const bf16x8*)(wb);
          bf16x8 w1 = *(const bf16x8*)(wb + 28672);       // gate stride 7*4*1024
          bf16x8 w2 = *(const bf16x8*)(wb + 2 * 28672);
          bf16x8 w3 = *(const bf16x8*)(wb + 3 * 28672);
          bf16x8 ha0 = *(const bf16x8*)(lhbuf + ((p - 1) & 1) * 8192 + 0 * 4096
                                        + kc * 1024 + lane * 16);
          bf16x8 ha1 = *(const bf16x8*)(lhbuf + ((p - 1) & 1) * 8192 + 1 * 4096
                                        + kc * 1024 + lane * 16);
          acc[0][0] = MFMA(ha0, w0, acc[0][0]);
          acc[0][1] = MFMA(ha0, w1, acc[0][1]);
          acc[0][2] = MFMA(ha0, w2, acc[0][2]);
          acc[0][3] = MFMA(ha0, w3, acc[0][3]);
          acc[1][0] = MFMA(ha1, w0, acc[1][0]);
          acc[1][1] = MFMA(ha1, w1, acc[1][1]);
          acc[1][2] = MFMA(ha1, w2, acc[1][2]);
          acc[1][3] = MFMA(ha1, w3, acc[1][3]);
        }
#pragma unroll
        for (int mt = 0; mt < 2; mt++) {
#pragma unroll
          for (int i = 0; i < 4; i++) {
            float ii = sigm(acc[mt][0][i]), ff = sigm(acc[mt][1][i]);
            float gg = tanh_(acc[mt][2][i]), oo = sigm(acc[mt][3][i]);
            float cn = __builtin_fmaf(ff, c[mt][i], ii * gg);
            c[mt][i] = cn;
            ((unsigned short*)(lhbuf + (p & 1) * 8192 + mt * 4096))
                [wbase + (q * 4 + i) * 8] = f2bf_fast(oo * tanh_(cn));
          }
        }
      }
      __syncthreads();
    }
  } else {
    // ================= logits role =================
    bf16x8 ow[2][4];
#pragma unroll
    for (int ct = 0; ct < 2; ct++)
#pragma unroll
      for (int kc = 0; kc < 4; kc++) {
        ow[ct][kc] = *(const bf16x8*)(outw + (size_t)(ct * 4 + kc) * 512 + lane * 8);
        force_frag(ow[ct][kc]);
      }
    float ob[2];
#pragma unroll
    for (int ct = 0; ct < 2; ct++) {
      int cv = ct * 16 + l15;
      ob[ct] = (cv < VV) ? out_b[cv] : 0.0f;
    }
    __syncthreads();                              // barrier A

    for (int p = 0; p < TT + 2; p++) {
      if (p >= 2) {
        const int t = p - 2;
#pragma unroll
        for (int mt = 0; mt < 2; mt++) {
          bf16x8 ha[4];
#pragma unroll
          for (int kc = 0; kc < 4; kc++)
            ha[kc] = *(const bf16x8*)(lhbuf + ((p - 1) & 1) * 8192 + mt * 4096
                                      + kc * 1024 + lane * 16);
#pragma unroll
          for (int ct = 0; ct < 2; ct++) {
            f32x4 acc = {ob[ct], ob[ct], ob[ct], ob[ct]};
#pragma unroll
            for (int kc = 0; kc < 4; kc++)
              acc = MFMA(ha[kc], ow[ct][kc], acc);
            int cv = ct * 16 + l15;
            if (cv < VV) {
#pragma unroll
              for (int i = 0; i < 4; i++) {
                int rowg = blk * 32 + mt * 16 + q * 4 + i;
                out[((size_t)rowg * TT + t) * VV + cv] = acc[i];
              }
            }
          }
        }
      }
      __syncthreads();
    }
  }
}

extern "C" void kernel_launch(void* const* d_in, const int* in_sizes, int n_in,
                              void* d_out, int out_size, void* d_ws, size_t ws_size,
                              hipStream_t stream) {
  (void)in_sizes; (void)n_in; (void)out_size; (void)ws_size;
  const float* z        = (const float*)d_in[0];
  const int*   x_in     = (const int*)  d_in[1];
  const float* emb      = (const float*)d_in[2];
  const float* fc_z_w   = (const float*)d_in[3];
  const float* fc_z_b   = (const float*)d_in[4];
  const float* gru_wih  = (const float*)d_in[5];
  const float* gru_whh  = (const float*)d_in[6];
  const float* gru_bih  = (const float*)d_in[7];
  const float* gru_bhh  = (const float*)d_in[8];
  const float* lstm_wih = (const float*)d_in[9];
  const float* lstm_whh = (const float*)d_in[10];
  const float* lstm_bih = (const float*)d_in[11];
  const float* lstm_bhh = (const float*)d_in[12];
  const float* out_w    = (const float*)d_in[13];
  const float* out_b    = (const float*)d_in[14];
  char*  ws  = (char*)d_ws;
  float* out = (float*)d_out;

  const unsigned short* gruw  = (const unsigned short*)(ws + OFF_GRUW);
  const unsigned short* tblp  = (const unsigned short*)(ws + OFF_TBL);
  const unsigned short* lstmw = (const unsigned short*)(ws + OFF_LSTMW);
  const unsigned short* outw  = (const unsigned short*)(ws + OFF_OUTW);
  const unsigned short* fczw  = (const unsigned short*)(ws + OFF_FCZW);
  const float*          lbias = (const float*)(ws + OFF_LBIAS);

  // allow >64 KB dynamic LDS (idempotent; not a stream op, capture-safe)
  hipFuncSetAttribute((const void*)fused_kernel,
                      hipFuncAttributeMaxDynamicSharedMemorySize, L_TOTAL);

  prep_kernel<<<136, 256, 0, stream>>>(fc_z_w, gru_whh, lstm_wih, lstm_whh,
                                       lstm_bih, lstm_bhh, out_w,
                                       emb, gru_wih, gru_bih, gru_bhh, ws);
  fused_kernel<<<256, 1024, L_TOTAL, stream>>>(z, x_in, fc_z_b, gru_bhh,
                                               gruw, tblp, fczw, lstmw, lbias,
                                               out_b, outw, out);
}

// Round 8
// 185.132 us; speedup vs baseline: 1.7249x; 1.0119x over previous
//
#include <hip/hip_runtime.h>
#include <stdint.h>
#include <stddef.h>

// Problem dims (fixed by reference)
#define BB 8192
#define TT 26
#define VV 23
#define EE 100
#define HH 128
#define LL 64

typedef __attribute__((ext_vector_type(8))) short bf16x8;  // 8 bf16 = 4 VGPRs
typedef __attribute__((ext_vector_type(4))) float f32x4;   // MFMA 16x16 C/D

#define MFMA(a, b, c) __builtin_amdgcn_mfma_f32_16x16x32_bf16((a), (b), (c), 0, 0, 0)

// ---------------- workspace layout (bytes) ----------------
#define OFF_GRUW   0ull                  // GRU Whh B-frags: 24ct*4kc*1024
#define OFF_TBL    98304ull              // one-hot table B-frags: 24ct*1024 (bih + bhh_r/z folded)
#define OFF_LSTMW  122880ull             // LSTM fused W B-frags: 28ct*8kc*1024 (kc0-3=y, kc4-7=h)
#define OFF_OUTW   352256ull             // out_w B-frags: 2ct*4kc*1024
#define OFF_FCZW   360448ull             // fc_z_w B-frags: 8ct*2kc*1024
#define OFF_LBIAS  376832ull             // fused LSTM bias 4*112 fp32

// Dynamic-LDS partition (bytes) — M=32 rows/block (R1 layout, proven)
#define L_LW    0              // LSTM h-half weight frags: 112 KB (28 ct * 4 kc * 1024)
#define L_HF    114688         // GRU y dbuf: 2 * 8192 (2 row-tiles * 4096)
#define L_LH    131072         // LSTM h dbuf: 2 * 8192
#define L_IDX   147456         // token idx: TT*32 = 832 (padded to 1024)
#define L_TOTAL 148480

__device__ __forceinline__ void force_frag(bf16x8& v) { asm volatile("" : "+v"(v)); }

// Exact RNE (prep only)
__device__ __forceinline__ unsigned short f2bf(float f) {
  union { float f; unsigned u; } v; v.f = f;
  unsigned u = v.u;
  return (unsigned short)((u + 0x7FFFu + ((u >> 16) & 1u)) >> 16);
}
// Fast in-loop convert (round-half-up)
__device__ __forceinline__ unsigned short f2bf_fast(float f) {
  union { float f; unsigned u; } v; v.f = f;
  return (unsigned short)((v.u + 0x8000u) >> 16);
}
#define LOG2E 1.4426950408889634f
__device__ __forceinline__ float sigm(float x) {
  return __builtin_amdgcn_rcpf(1.0f + __builtin_amdgcn_exp2f(-x * LOG2E));
}
__device__ __forceinline__ float tanh_(float x) {
  return __builtin_fmaf(-2.0f,
      __builtin_amdgcn_rcpf(1.0f + __builtin_amdgcn_exp2f(x * (2.0f * LOG2E))), 1.0f);
}

__device__ __forceinline__ bf16x8 cvt8(f32x4 a, f32x4 b) {
  bf16x8 o;
#pragma unroll
  for (int j = 0; j < 4; j++) {
    o[j]     = (short)f2bf(a[j]);
    o[4 + j] = (short)f2bf(b[j]);
  }
  return o;
}

// =====================================================================
// K0 (R6): vectorized prep. Each thread builds one 16-B bf16x8 fragment
// chunk from two aligned f32x4 global loads (swizzle is contiguous in j).
// =====================================================================
__global__ __launch_bounds__(256) void prep_kernel(
    const float* __restrict__ fc_z_w, const float* __restrict__ gru_whh,
    const float* __restrict__ lstm_wih, const float* __restrict__ lstm_whh,
    const float* __restrict__ lstm_bih, const float* __restrict__ lstm_bhh,
    const float* __restrict__ out_w,
    const float* __restrict__ emb, const float* __restrict__ gru_wih,
    const float* __restrict__ gru_bih, const float* __restrict__ gru_bhh,
    char* __restrict__ ws)
{
  __shared__ float emb_s[VV * EE];
  __shared__ float wih_s[16 * EE];
  __shared__ float bih_s[16];
  const int blk = blockIdx.x;
  const int tid = threadIdx.x;

  if (blk < 86) {
    const int ch = blk * 256 + tid;          // 0..22015
    bf16x8 o = {0, 0, 0, 0, 0, 0, 0, 0};
    if (ch < 6144) {
      int lane = ch & 63, kc = (ch >> 6) & 3, ct = ch >> 8;
      int n  = ct * 16 + (lane & 15);
      int k0 = kc * 32 + ((lane >> 4) & 3) * 8;
      const float* s = gru_whh + (size_t)n * HH + k0;
      o = cvt8(*(const f32x4*)s, *(const f32x4*)(s + 4));
      ((bf16x8*)(ws + OFF_GRUW))[ch] = o;
    } else if (ch < 20480) {
      int c2 = ch - 6144;
      int lane = c2 & 63, kc = (c2 >> 6) & 7, ct = c2 >> 9;
      int row = ct * 16 + (lane & 15);
      int g = row / 112, cc = row % 112;
      int q = (lane >> 4) & 3;
      if (cc < EE) {
        if (kc < 4) {
          const float* s = lstm_wih + (size_t)(g * EE + cc) * HH + kc * 32 + q * 8;
          o = cvt8(*(const f32x4*)s, *(const f32x4*)(s + 4));
        } else {
          int k0 = (kc - 4) * 32 + q * 8;
          const float* s = lstm_whh + (size_t)(g * EE + cc) * EE + k0;
          if (k0 + 8 <= EE) {
            o = cvt8(*(const f32x4*)s, *(const f32x4*)(s + 4));
          } else if (k0 < EE) {
            f32x4 a = *(const f32x4*)s;
#pragma unroll
            for (int j = 0; j < 4; j++) o[j] = (short)f2bf(a[j]);
          }
        }
      }
      ((bf16x8*)(ws + OFF_LSTMW))[c2] = o;
    } else if (ch < 20992) {
      int c3 = ch - 20480;
      int lane = c3 & 63, kc = (c3 >> 6) & 3, ct = c3 >> 8;
      int n  = ct * 16 + (lane & 15);
      int k0 = kc * 32 + ((lane >> 4) & 3) * 8;
      if (n < VV) {
        const float* s = out_w + (size_t)n * EE + k0;
        if (k0 + 8 <= EE) {
          o = cvt8(*(const f32x4*)s, *(const f32x4*)(s + 4));
        } else if (k0 < EE) {
          f32x4 a = *(const f32x4*)s;
#pragma unroll
          for (int j = 0; j < 4; j++) o[j] = (short)f2bf(a[j]);
        }
      }
      ((bf16x8*)(ws + OFF_OUTW))[c3] = o;
    } else {
      int c4 = ch - 20992;
      int lane = c4 & 63, kc = (c4 >> 6) & 1, ct = c4 >> 7;
      int n  = ct * 16 + (lane & 15);
      int k0 = kc * 32 + ((lane >> 4) & 3) * 8;
      const float* s = fc_z_w + (size_t)n * LL + k0;
      o = cvt8(*(const f32x4*)s, *(const f32x4*)(s + 4));
      ((bf16x8*)(ws + OFF_FCZW))[c4] = o;
    }
    return;
  }

  if (blk < 88) {
    int idx = (blk - 86) * 256 + tid;
    if (idx < 448) {
      int g = idx / 112, c = idx % 112;
      float v = (c < EE) ? (lstm_bih[g * EE + c] + lstm_bhh[g * EE + c]) : 0.0f;
      *(float*)(ws + OFF_LBIAS + (size_t)idx * 4) = v;
    }
    return;
  }

  // ---- one-hot table part (blocks 88..135; 2 per ct) ----
  const int blk2 = blk - 88;           // 0..47
  const int ct   = blk2 >> 1;          // 0..23
  const int half = blk2 & 1;
  const int n0   = ct * 16;

  for (int i = tid; i < VV * EE; i += 256) emb_s[i] = emb[i];
  for (int i = tid; i < 16 * EE; i += 256) wih_s[i] = gru_wih[n0 * EE + i];
  if (tid < 16) bih_s[tid] = gru_bih[n0 + tid];
  __syncthreads();

  const int t512 = half * 256 + tid;   // 0..511 within ct
  const int j    = t512 & 7;
  const int lane = (t512 >> 3) & 63;
  const int n16  = lane & 15;
  const int k    = ((lane >> 4) & 3) * 8 + j;
  const int g    = ct >> 3;            // gate 0=r 1=z 2=n
  float v = 0.0f;
  if (k < VV) {
    const float* ep = emb_s + k * EE;
    const float* wp = wih_s + n16 * EE;
    float s0 = 0.f, s1 = 0.f, s2 = 0.f, s3 = 0.f;
#pragma unroll 5
    for (int m = 0; m < EE; m += 4) {
      s0 += ep[m] * wp[m];         s1 += ep[m + 1] * wp[m + 1];
      s2 += ep[m + 2] * wp[m + 2]; s3 += ep[m + 3] * wp[m + 3];
    }
    v = bih_s[n16] + ((s0 + s1) + (s2 + s3));
    if (g < 2) v += gru_bhh[g * HH + (ct & 7) * 16 + n16];
  }
  *(unsigned short*)(ws + OFF_TBL + (size_t)(ct * 512 + t512) * 2) = f2bf(v);
}

// =====================================================================
// K1: FUSED gru+lstm+logits. 256 blocks x 1024 thr (16 waves), 32 rows.
// R7: two phase-start-burst relievers on the proven barrier structure:
//  (1) GRU one-hot hoist: oh-build + 3 one-hot MFMAs depend only on
//      idx_lds+tw (phase-invariant) -> computed BEFORE the barrier in
//      GRU's slack (while LSTM runs its epilogue). Removes 6 MFMA +
//      ~32 VALU + idx reads per GRU wave from the contended window.
//  (2) s_setprio(1) around the LSTM read+MFMA region (the 64-MFMA
//      phase pole): scheduler favors critical waves during the burst.
//   waves 0-7  (GRU):    step p      y(p)   -> hfrag[(p+1)&1]
//   waves 8-14 (LSTM):   step p-1    h(p-1) -> lhbuf[p&1]
//   wave 15    (logits): step p-2    -> out
// =====================================================================
__global__ __launch_bounds__(1024, 4) void fused_kernel(
    const float* __restrict__ z, const int* __restrict__ x_in,
    const float* __restrict__ fc_z_b, const float* __restrict__ gru_bhh,
    const unsigned short* __restrict__ gruw, const unsigned short* __restrict__ tbl,
    const unsigned short* __restrict__ fczw,
    const unsigned short* __restrict__ lstmw, const float* __restrict__ lbias,
    const float* __restrict__ out_b, const unsigned short* __restrict__ outw,
    float* __restrict__ out)
{
  extern __shared__ char smem[];
  unsigned short* lwlds = (unsigned short*)(smem + L_LW);   // h-half weight frags
  char*           hfrag = smem + L_HF;                      // [buf]*8192 B, tile mt at mt*4096
  char*           lhbuf = smem + L_LH;                      // [buf]*8192 B
  unsigned char*  idx_lds = (unsigned char*)(smem + L_IDX);

  const int tid  = threadIdx.x;
  const int wv   = tid >> 6;        // 0..15
  const int lane = tid & 63;
  const int l15  = lane & 15;
  const int q    = (lane >> 4) & 3;
  const int blk  = blockIdx.x;      // 0..255

  // cooperative: zero LSTM h state (both buffers) + stage h-half weight frags
  for (int i = tid; i < 8192; i += 1024)
    ((unsigned short*)lhbuf)[i] = 0;
  for (int f = tid; f < 7168; f += 1024) {          // 7168 b128 chunks = 112 KB
    int frag_i = f >> 6, within = f & 63;
    int ct = frag_i >> 2, kcl = frag_i & 3;
    *(bf16x8*)((char*)lwlds + (size_t)frag_i * 1024 + within * 16) =
        *(const bf16x8*)(lstmw + ((size_t)(ct * 8 + 4 + kcl)) * 512 + within * 8);
  }

  if (wv < 8) {
    // ================= GRU role =================
    {
      int rid = wv * 64 + lane;     // 0..511
      for (int i = rid; i < TT * 32; i += 512) {
        int t = i >> 5, r = i & 31;
        idx_lds[i] = (unsigned char)x_in[(blk * 32 + r) * TT + t];
      }
    }
    bf16x8 gw[3][4], tw[3];
#pragma unroll
    for (int g = 0; g < 3; g++) {
      int ct = g * 8 + wv;
#pragma unroll
      for (int kc = 0; kc < 4; kc++) {
        gw[g][kc] = *(const bf16x8*)(gruw + (size_t)(ct * 4 + kc) * 512 + lane * 8);
        force_frag(gw[g][kc]);
      }
      tw[g] = *(const bf16x8*)(tbl + (size_t)ct * 512 + lane * 8);
      force_frag(tw[g]);
    }
    const int col = wv * 16 + l15;
    const float b_n = gru_bhh[2 * HH + col];   // r,z biases folded into tbl
    const int wbase = (col >> 5) * 512 + ((col >> 3) & 3) * 128 + (col & 7);

    // h0 = tanh(z @ fc_z_w^T + fc_z_b), two row-tiles
    float h[2][4];
    {
      bf16x8 fw0 = *(const bf16x8*)(fczw + (size_t)(wv * 2 + 0) * 512 + lane * 8);
      bf16x8 fw1 = *(const bf16x8*)(fczw + (size_t)(wv * 2 + 1) * 512 + lane * 8);
      float fzb = fc_z_b[col];
#pragma unroll
      for (int mt = 0; mt < 2; mt++) {
        const float* zp = z + (size_t)(blk * 32 + mt * 16 + l15) * LL + q * 8;
        f32x4 z0 = *(const f32x4*)(zp);
        f32x4 z1 = *(const f32x4*)(zp + 4);
        f32x4 z2 = *(const f32x4*)(zp + 32);
        f32x4 z3 = *(const f32x4*)(zp + 36);
        bf16x8 za0, za1;
#pragma unroll
        for (int j = 0; j < 4; j++) {
          za0[j]     = (short)f2bf(z0[j]);
          za0[4 + j] = (short)f2bf(z1[j]);
          za1[j]     = (short)f2bf(z2[j]);
          za1[4 + j] = (short)f2bf(z3[j]);
        }
        f32x4 acc = {fzb, fzb, fzb, fzb};
        acc = MFMA(za0, fw0, acc);
        acc = MFMA(za1, fw1, acc);
#pragma unroll
        for (int i = 0; i < 4; i++) {
          h[mt][i] = tanh_(acc[i]);
          ((unsigned short*)(hfrag + mt * 4096))[wbase + (q * 4 + i) * 8]
              = f2bf_fast(h[mt][i]);
        }
      }
    }
    __syncthreads();                              // barrier A

    // hoisted one-hot partials for phase p (r, z, xn)
    f32x4 pr[2], pz[2], px[2];
    {
#pragma unroll
      for (int mt = 0; mt < 2; mt++) {
        int iv = idx_lds[mt * 16 + l15];          // p = 0
        bf16x8 oh;
#pragma unroll
        for (int j = 0; j < 8; j++)
          oh[j] = (short)((iv == q * 8 + j) ? 0x3F80 : 0);
        f32x4 zz = {0.0f, 0.0f, 0.0f, 0.0f};
        pr[mt] = MFMA(oh, tw[0], zz);
        pz[mt] = MFMA(oh, tw[1], zz);
        px[mt] = MFMA(oh, tw[2], zz);
      }
    }

    for (int p = 0; p < TT + 2; p++) {
      if (p < TT) {
#pragma unroll
        for (int mt = 0; mt < 2; mt++) {
          f32x4 ar  = pr[mt];                     // one-hot partial (pre-barrier)
          f32x4 az  = pz[mt];
          f32x4 axn = px[mt];
          f32x4 ahn = {b_n, b_n, b_n, b_n};

          bf16x8 a[4];
#pragma unroll
          for (int kc = 0; kc < 4; kc++)
            a[kc] = *(const bf16x8*)(hfrag + (p & 1) * 8192 + mt * 4096
                                     + kc * 1024 + lane * 16);
#pragma unroll
          for (int kc = 0; kc < 4; kc++) {
            ar  = MFMA(a[kc], gw[0][kc], ar);
            az  = MFMA(a[kc], gw[1][kc], az);
            ahn = MFMA(a[kc], gw[2][kc], ahn);
          }
#pragma unroll
          for (int i = 0; i < 4; i++) {
            float r  = sigm(ar[i]);
            float zg = sigm(az[i]);
            float n  = tanh_(__builtin_fmaf(r, ahn[i], axn[i]));
            h[mt][i] = __builtin_fmaf(zg, h[mt][i] - n, n);
            ((unsigned short*)(hfrag + ((p + 1) & 1) * 8192 + mt * 4096))
                [wbase + (q * 4 + i) * 8] = f2bf_fast(h[mt][i]);
          }
        }
        // pre-compute next phase's one-hot partials in this phase's slack
        if (p + 1 < TT) {
#pragma unroll
          for (int mt = 0; mt < 2; mt++) {
            int iv = idx_lds[(p + 1) * 32 + mt * 16 + l15];
            bf16x8 oh;
#pragma unroll
            for (int j = 0; j < 8; j++)
              oh[j] = (short)((iv == q * 8 + j) ? 0x3F80 : 0);
            f32x4 zz = {0.0f, 0.0f, 0.0f, 0.0f};
            pr[mt] = MFMA(oh, tw[0], zz);
            pz[mt] = MFMA(oh, tw[1], zz);
            px[mt] = MFMA(oh, tw[2], zz);
          }
        }
      }
      __syncthreads();
    }
  } else if (wv < 15) {
    // ================= LSTM role =================
    const int tile = wv - 8;        // 0..6
    // y-half weights kc0..2 in registers (48 regs); kc3 streamed from global.
    bf16x8 lwy[4][3];
#pragma unroll
    for (int g = 0; g < 4; g++)
#pragma unroll
      for (int kc = 0; kc < 3; kc++) {
        lwy[g][kc] = *(const bf16x8*)(lstmw + (size_t)((g * 7 + tile) * 8 + kc) * 512 + lane * 8);
        force_frag(lwy[g][kc]);
      }
    const int col = tile * 16 + l15;
    float b[4];
#pragma unroll
    for (int g = 0; g < 4; g++) b[g] = lbias[g * 112 + col];
    const int wbase = (col >> 5) * 512 + ((col >> 3) & 3) * 128 + (col & 7);
    float c[2][4] = {{0, 0, 0, 0}, {0, 0, 0, 0}};
    __syncthreads();                              // barrier A

    for (int p = 0; p < TT + 2; p++) {
      if (p >= 1 && p <= TT) {
        __builtin_amdgcn_s_setprio(1);            // LSTM = phase pole
        // y-kc3 weights from global (L1-hot after step 0); issue early.
        bf16x8 yw3[4];
#pragma unroll
        for (int g = 0; g < 4; g++)
          yw3[g] = *(const bf16x8*)(lstmw + (size_t)((g * 7 + tile) * 8 + 3) * 512 + lane * 8);

        f32x4 acc[2][4];
#pragma unroll
        for (int mt = 0; mt < 2; mt++)
#pragma unroll
          for (int g = 0; g < 4; g++) {
            f32x4 ini = {b[g], b[g], b[g], b[g]};
            acc[mt][g] = ini;
          }

        // y-half kc0..2: reg weights, both row-tiles
#pragma unroll
        for (int kc = 0; kc < 3; kc++) {
          bf16x8 ya0 = *(const bf16x8*)(hfrag + (p & 1) * 8192 + 0 * 4096
                                        + kc * 1024 + lane * 16);
          bf16x8 ya1 = *(const bf16x8*)(hfrag + (p & 1) * 8192 + 1 * 4096
                                        + kc * 1024 + lane * 16);
#pragma unroll
          for (int g = 0; g < 4; g++) {
            acc[0][g] = MFMA(ya0, lwy[g][kc], acc[0][g]);
            acc[1][g] = MFMA(ya1, lwy[g][kc], acc[1][g]);
          }
        }
        // y-half kc3: streamed weights
        {
          bf16x8 ya0 = *(const bf16x8*)(hfrag + (p & 1) * 8192 + 0 * 4096
                                        + 3 * 1024 + lane * 16);
          bf16x8 ya1 = *(const bf16x8*)(hfrag + (p & 1) * 8192 + 1 * 4096
                                        + 3 * 1024 + lane * 16);
#pragma unroll
          for (int g = 0; g < 4; g++) {
            acc[0][g] = MFMA(ya0, yw3[g], acc[0][g]);
            acc[1][g] = MFMA(ya1, yw3[g], acc[1][g]);
          }
        }
        // h-half: LDS weights read ONCE per kc (shared across both row-tiles)
#pragma unroll
        for (int kc = 0; kc < 4; kc++) {
          const char* wb = (const char*)lwlds + (size_t)(tile * 4 + kc) * 1024 + lane * 16;
          bf16x8 w0 = *(const bf16x8*)(wb);
          bf16x8 w1 = *(const bf16x8*)(wb + 28672);       // gate stride 7*4*1024
          bf16x8 w2 = *(const bf16x8*)(wb + 2 * 28672);
          bf16x8 w3 = *(const bf16x8*)(wb + 3 * 28672);
          bf16x8 ha0 = *(const bf16x8*)(lhbuf + ((p - 1) & 1) * 8192 + 0 * 4096
                                        + kc * 1024 + lane * 16);
          bf16x8 ha1 = *(const bf16x8*)(lhbuf + ((p - 1) & 1) * 8192 + 1 * 4096
                                        + kc * 1024 + lane * 16);
          acc[0][0] = MFMA(ha0, w0, acc[0][0]);
          acc[0][1] = MFMA(ha0, w1, acc[0][1]);
          acc[0][2] = MFMA(ha0, w2, acc[0][2]);
          acc[0][3] = MFMA(ha0, w3, acc[0][3]);
          acc[1][0] = MFMA(ha1, w0, acc[1][0]);
          acc[1][1] = MFMA(ha1, w1, acc[1][1]);
          acc[1][2] = MFMA(ha1, w2, acc[1][2]);
          acc[1][3] = MFMA(ha1, w3, acc[1][3]);
        }
        __builtin_amdgcn_s_setprio(0);
#pragma unroll
        for (int mt = 0; mt < 2; mt++) {
#pragma unroll
          for (int i = 0; i < 4; i++) {
            float ii = sigm(acc[mt][0][i]), ff = sigm(acc[mt][1][i]);
            float gg = tanh_(acc[mt][2][i]), oo = sigm(acc[mt][3][i]);
            float cn = __builtin_fmaf(ff, c[mt][i], ii * gg);
            c[mt][i] = cn;
            ((unsigned short*)(lhbuf + (p & 1) * 8192 + mt * 4096))
                [wbase + (q * 4 + i) * 8] = f2bf_fast(oo * tanh_(cn));
          }
        }
      }
      __syncthreads();
    }
  } else {
    // ================= logits role =================
    bf16x8 ow[2][4];
#pragma unroll
    for (int ct = 0; ct < 2; ct++)
#pragma unroll
      for (int kc = 0; kc < 4; kc++) {
        ow[ct][kc] = *(const bf16x8*)(outw + (size_t)(ct * 4 + kc) * 512 + lane * 8);
        force_frag(ow[ct][kc]);
      }
    float ob[2];
#pragma unroll
    for (int ct = 0; ct < 2; ct++) {
      int cv = ct * 16 + l15;
      ob[ct] = (cv < VV) ? out_b[cv] : 0.0f;
    }
    __syncthreads();                              // barrier A

    for (int p = 0; p < TT + 2; p++) {
      if (p >= 2) {
        const int t = p - 2;
#pragma unroll
        for (int mt = 0; mt < 2; mt++) {
          bf16x8 ha[4];
#pragma unroll
          for (int kc = 0; kc < 4; kc++)
            ha[kc] = *(const bf16x8*)(lhbuf + ((p - 1) & 1) * 8192 + mt * 4096
                                      + kc * 1024 + lane * 16);
#pragma unroll
          for (int ct = 0; ct < 2; ct++) {
            f32x4 acc = {ob[ct], ob[ct], ob[ct], ob[ct]};
#pragma unroll
            for (int kc = 0; kc < 4; kc++)
              acc = MFMA(ha[kc], ow[ct][kc], acc);
            int cv = ct * 16 + l15;
            if (cv < VV) {
#pragma unroll
              for (int i = 0; i < 4; i++) {
                int rowg = blk * 32 + mt * 16 + q * 4 + i;
                out[((size_t)rowg * TT + t) * VV + cv] = acc[i];
              }
            }
          }
        }
      }
      __syncthreads();
    }
  }
}

extern "C" void kernel_launch(void* const* d_in, const int* in_sizes, int n_in,
                              void* d_out, int out_size, void* d_ws, size_t ws_size,
                              hipStream_t stream) {
  (void)in_sizes; (void)n_in; (void)out_size; (void)ws_size;
  const float* z        = (const float*)d_in[0];
  const int*   x_in     = (const int*)  d_in[1];
  const float* emb      = (const float*)d_in[2];
  const float* fc_z_w   = (const float*)d_in[3];
  const float* fc_z_b   = (const float*)d_in[4];
  const float* gru_wih  = (const float*)d_in[5];
  const float* gru_whh  = (const float*)d_in[6];
  const float* gru_bih  = (const float*)d_in[7];
  const float* gru_bhh  = (const float*)d_in[8];
  const float* lstm_wih = (const float*)d_in[9];
  const float* lstm_whh = (const float*)d_in[10];
  const float* lstm_bih = (const float*)d_in[11];
  const float* lstm_bhh = (const float*)d_in[12];
  const float* out_w    = (const float*)d_in[13];
  const float* out_b    = (const float*)d_in[14];
  char*  ws  = (char*)d_ws;
  float* out = (float*)d_out;

  const unsigned short* gruw  = (const unsigned short*)(ws + OFF_GRUW);
  const unsigned short* tblp  = (const unsigned short*)(ws + OFF_TBL);
  const unsigned short* lstmw = (const unsigned short*)(ws + OFF_LSTMW);
  const unsigned short* outw  = (const unsigned short*)(ws + OFF_OUTW);
  const unsigned short* fczw  = (const unsigned short*)(ws + OFF_FCZW);
  const float*          lbias = (const float*)(ws + OFF_LBIAS);

  // allow >64 KB dynamic LDS (idempotent; not a stream op, capture-safe)
  hipFuncSetAttribute((const void*)fused_kernel,
                      hipFuncAttributeMaxDynamicSharedMemorySize, L_TOTAL);

  prep_kernel<<<136, 256, 0, stream>>>(fc_z_w, gru_whh, lstm_wih, lstm_whh,
                                       lstm_bih, lstm_bhh, out_w,
                                       emb, gru_wih, gru_bih, gru_bhh, ws);
  fused_kernel<<<256, 1024, L_TOTAL, stream>>>(z, x_in, fc_z_b, gru_bhh,
                                               gruw, tblp, fczw, lstmw, lbias,
                                               out_b, outw, out);
}